// Round 9
// baseline (1756.423 us; speedup 1.0000x reference)
//
#include <hip/hip_runtime.h>
#include <hip/hip_bf16.h>

#define T_STEPS 128
#define B_SZ    1024
#define IN_SZ   47
#define H_SZ    646
#define OUT_SZ  5

#define XK    96      // xs padded row stride (47 -> 96)
#define K0    768     // layer0 K = 96 + 672
#define K1    1344    // layer1 K = 672 + 672 (also the state-slab row stride)
#define N0PAD 704     // L0 cols padded (11 * 64)
#define N1PAD 672     // L1 cols padded (21 * 32)
#define RING  17      // state ring slots per row-group (fresh-address coherence)
#define SLAB  172032  // 128 rows * 1344 cols, elements per rg slab
#define FSTR  160     // flag array stride (ints), 640 B -> no cross-rg line sharing

#define TW0   72      // L0 LDS tile stride (64 cols + 8 pad: bank-safe, 16B-aligned rows)
#define TW1   40      // L1 LDS tile stride (32 cols + 8 pad)
#define W0W   49152   // W0 LDS words (ush): 96 KB
#define W1W   43008   // W1 LDS words (ush): 84 KB

typedef __hip_bfloat16 bf16;
typedef unsigned short ush;
typedef unsigned long long u64;
using frag8 = __attribute__((ext_vector_type(8))) short;  // 8 bf16
using f32x4 = __attribute__((ext_vector_type(4))) float;

// ---------------------------------------------------------------- prep kernels

__global__ void prep_xs(const float* __restrict__ xs, bf16* __restrict__ xs_pad) {
    int idx = blockIdx.x * blockDim.x + threadIdx.x;
    if (idx >= T_STEPS * B_SZ * XK) return;
    int k = idx % XK;
    int rb = idx / XK;
    float v = (k < IN_SZ) ? xs[(size_t)rb * IN_SZ + k] : 0.f;
    xs_pad[idx] = __float2bfloat16(v);
}

__global__ void pack_w0(const float* __restrict__ Wih, const float* __restrict__ Whh,
                        bf16* __restrict__ Wc) {
    int idx = blockIdx.x * blockDim.x + threadIdx.x;
    if (idx >= N0PAD * K0) return;
    int j = idx / K0, k = idx % K0;
    float v = 0.f;
    if (j < H_SZ) {
        if (k < IN_SZ)                      v = Wih[(size_t)j * IN_SZ + k];
        else if (k >= XK && k < XK + H_SZ)  v = Whh[(size_t)j * H_SZ + (k - XK)];
    }
    Wc[idx] = __float2bfloat16(v);
}

__global__ void pack_w1(const float* __restrict__ Wih, const float* __restrict__ Whh,
                        bf16* __restrict__ Wc) {
    int idx = blockIdx.x * blockDim.x + threadIdx.x;
    if (idx >= N1PAD * K1) return;
    int j = idx / K1, k = idx % K1;
    float v = 0.f;
    if (j < H_SZ) {
        if (k < H_SZ)                          v = Wih[(size_t)j * H_SZ + k];
        else if (k >= 672 && k < 672 + H_SZ)   v = Whh[(size_t)j * H_SZ + (k - 672)];
    }
    Wc[idx] = __float2bfloat16(v);
}

__global__ void pack_bias(const float* __restrict__ bi, const float* __restrict__ bh,
                          float* __restrict__ b, int n) {
    int j = blockIdx.x * blockDim.x + threadIdx.x;
    if (j >= n) return;
    b[j] = (j < H_SZ) ? (bi[j] + bh[j]) : 0.f;
}

// ---------------------------------------------------------------- persistent RNN
// r4/r8-proven skeleton and sync semantics. New vs r8:
//  (a) Epilogue: tanh results scatter to an LDS tile (padded stride), then a
//      cooperative copy-out issues 8-B relaxed AGENT-scope stores, fully
//      coalesced (4 lanes = one 64-B line). Same visibility semantics as the
//      proven 2-B agent-store path, ~16x fewer store transactions.
//  (b) sched_barrier(0) ONCE between the A-load batch and the MFMA loop pins
//      all loads before all MFMAs -> 42-deep MLP (r8's preload was silently
//      sunk by the scheduler; VGPR_Count 44 proved it).

__device__ __forceinline__ ush tanh_bits(float x) {
    x = fminf(fmaxf(x, -15.f), 15.f);
    float e = __expf(2.f * x);
    bf16 hb = __float2bfloat16((e - 1.f) / (e + 1.f));
    return *(ush*)&hb;
}

__device__ __forceinline__ void st8(u64* dst, u64 v) {
    __hip_atomic_store(dst, v, __ATOMIC_RELAXED, __HIP_MEMORY_SCOPE_AGENT);
}

__device__ __forceinline__ void poll_ge(int* p, int need) {
    while (__hip_atomic_load(p, __ATOMIC_RELAXED, __HIP_MEMORY_SCOPE_AGENT) < need)
        __builtin_amdgcn_s_sleep(1);
}

__global__ __launch_bounds__(512, 2) void persist(
    const bf16* __restrict__ xs_pad, const bf16* __restrict__ Wc0,
    const bf16* __restrict__ Wc1, const float* __restrict__ b0,
    const float* __restrict__ b1, bf16* __restrict__ Sring,
    int* __restrict__ flags)
{
    extern __shared__ ush Wlds[];
    const int bid  = blockIdx.x;
    const int rg   = bid & 7;
    const int c8   = bid >> 3;
    const bool isL0 = (c8 < 11);
    const int tid  = threadIdx.x;
    const int wv   = tid >> 6;
    const int lane = tid & 63;
    const int q8   = (lane >> 4) * 8;    // fragment k offset (elements)
    const int l15  = lane & 15;

    ush* const ShT = Wlds + (isL0 ? W0W : W1W);   // LDS transpose tile

    // ---- stage W slice into LDS in fragment order + zero tile (once) ----
    if (isL0) {
        const int col0 = c8 * 64;
        for (int g = wv; g < 96; g += 8) {            // g = kc*4 + ct
            int kc = g >> 2, ct = g & 3;
            const bf16* src = Wc0 + (size_t)(col0 + ct*16 + l15) * K0 + kc*32 + q8;
            *(uint4*)&Wlds[g*512 + lane*8] = *(const uint4*)src;
        }
        for (int i = tid; i < 128*TW0; i += 512) ShT[i] = 0;
    } else {
        const int col0 = (c8 - 11) * 32;
        for (int g = wv; g < 84; g += 8) {            // g = kc*2 + ct
            int kc = g >> 1, ct = g & 1;
            const bf16* src = Wc1 + (size_t)(col0 + ct*16 + l15) * K1 + kc*32 + q8;
            *(uint4*)&Wlds[g*512 + lane*8] = *(const uint4*)src;
        }
        for (int i = tid; i < 128*TW1; i += 512) ShT[i] = 0;
    }
    __syncthreads();

    const int loc = wv * 16 + l15;      // this wave's A-fragment row (16 rows/wave)
    bf16* const ringbase = Sring + (size_t)rg * RING * SLAB;
    int*  const fL0 = flags + rg * FSTR;          // 11 publishers
    int*  const fL1 = flags + (8 + rg) * FSTR;    // 21 publishers

    if (isL0) {
        const int col0 = c8 * 64;
        float bias[4];
        #pragma unroll
        for (int ct = 0; ct < 4; ++ct) bias[ct] = b0[col0 + ct*16 + l15];
        // copy-out geometry: 8 threads/row, 8-col chunks
        const int crow = tid >> 3, ccb = tid & 7;
        const bool cok = (col0 + ccb*8) < 672;    // clip c8=10 into h0 region only

        for (int p = 0; p < 128; ++p) {
            if (tid == 0) {
                if (p > 0)   poll_ge(&fL0[p-1], 11);
                if (p >= 17) poll_ge(&fL1[p-16], 21);   // WAR: slot p%17 readers done
            }
            __syncthreads();
            if (p >= RING + 1 && (p - 1) % RING == 0)
                __builtin_amdgcn_fence(__ATOMIC_ACQUIRE, "agent");
            const bf16* rsl = ringbase + (size_t)((p + RING - 1) % RING) * SLAB;
            bf16*       wsl = ringbase + (size_t)(p % RING) * SLAB;

            // A = [x_t(96) | h0(p-1)(672)], C = h0(p) -> slab cols [0,672)
            const bf16* xr = xs_pad + ((size_t)p * B_SZ + rg*128 + loc) * XK + q8;
            const bf16* hr = rsl + (size_t)loc * K1 + q8;
            uint4 abuf[24];
            #pragma unroll
            for (int i = 0; i < 24; ++i)
                abuf[i] = (i < 3) ? *(const uint4*)(xr + i*32)
                                  : *(const uint4*)(hr + (i-3)*32);
            __builtin_amdgcn_sched_barrier(0);   // pin: all loads before MFMAs
            f32x4 acc[4] = {};
            #pragma unroll
            for (int kc = 0; kc < 24; ++kc) {
                frag8 af = *(const frag8*)&abuf[kc];
                #pragma unroll
                for (int ct = 0; ct < 4; ++ct) {
                    frag8 wf = *(const frag8*)&Wlds[(kc*4+ct)*512 + lane*8];
                    acc[ct] = __builtin_amdgcn_mfma_f32_16x16x32_bf16(
                        af, wf, acc[ct], 0, 0, 0);
                }
            }
            // scatter tanh -> LDS tile (pad cols stay zero: guarded)
            const int rbase = wv*16 + (lane>>4)*4;
            #pragma unroll
            for (int ct = 0; ct < 4; ++ct) {
                const int tcol = ct*16 + l15;
                if (col0 + tcol < H_SZ) {
                    #pragma unroll
                    for (int i = 0; i < 4; ++i)
                        ShT[(rbase+i)*TW0 + tcol] = tanh_bits(acc[ct][i] + bias[ct]);
                }
            }
            __syncthreads();
            // coalesced copy-out: 2 rounds x (row, 8-col chunk) as 2x8B agent stores
            if (cok) {
                #pragma unroll
                for (int it = 0; it < 2; ++it) {
                    const int r = crow + it*64;
                    const u64* s = (const u64*)&ShT[r*TW0 + ccb*8];
                    u64* d = (u64*)(wsl + (size_t)r*K1 + col0 + ccb*8);
                    st8(d, s[0]); st8(d+1, s[1]);
                }
            }
            __syncthreads();   // per-wave vmcnt(0) drain before publish
            if (tid == 0)
                __hip_atomic_fetch_add(&fL0[p], 1, __ATOMIC_RELAXED,
                                       __HIP_MEMORY_SCOPE_AGENT);
        }
    } else {
        const int col0 = (c8 - 11) * 32;
        float bias[2];
        #pragma unroll
        for (int ct = 0; ct < 2; ++ct) bias[ct] = b1[col0 + ct*16 + l15];
        const int crow = tid >> 2, ccb = tid & 3;   // 4 threads/row

        for (int q = 1; q <= 128; ++q) {
            if (tid == 0) {
                poll_ge(&fL0[q-1], 11);              // h0(q-1) ready
                if (q > 1) poll_ge(&fL1[q-1], 21);   // h1(q-2) ready
            }
            __syncthreads();
            if (q >= RING + 1 && (q - 1) % RING == 0)
                __builtin_amdgcn_fence(__ATOMIC_ACQUIRE, "agent");
            const bf16* rsl = ringbase + (size_t)((q + RING - 1) % RING) * SLAB;
            bf16*       wsl = ringbase + (size_t)(q % RING) * SLAB;

            // A = slab row [h0(q-1) | h1(q-2)] (contiguous K=1344)
            const bf16* ar = rsl + (size_t)loc * K1 + q8;
            uint4 abuf[42];
            #pragma unroll
            for (int i = 0; i < 42; ++i) abuf[i] = *(const uint4*)(ar + i*32);
            __builtin_amdgcn_sched_barrier(0);   // pin: all loads before MFMAs
            f32x4 acc[2] = {};
            #pragma unroll
            for (int kc = 0; kc < 42; ++kc) {
                frag8 af = *(const frag8*)&abuf[kc];
                #pragma unroll
                for (int ct = 0; ct < 2; ++ct) {
                    frag8 wf = *(const frag8*)&Wlds[(kc*2+ct)*512 + lane*8];
                    acc[ct] = __builtin_amdgcn_mfma_f32_16x16x32_bf16(
                        af, wf, acc[ct], 0, 0, 0);
                }
            }
            const int rbase = wv*16 + (lane>>4)*4;
            #pragma unroll
            for (int ct = 0; ct < 2; ++ct) {
                const int tcol = ct*16 + l15;
                if (col0 + tcol < H_SZ) {
                    #pragma unroll
                    for (int i = 0; i < 4; ++i)
                        ShT[(rbase+i)*TW1 + tcol] = tanh_bits(acc[ct][i] + bias[ct]);
                }
            }
            __syncthreads();
            {   // coalesced copy-out -> h1 region
                const u64* s = (const u64*)&ShT[crow*TW1 + ccb*8];
                u64* d = (u64*)(wsl + (size_t)crow*K1 + 672 + col0 + ccb*8);
                st8(d, s[0]); st8(d+1, s[1]);
            }
            __syncthreads();   // per-wave vmcnt(0) drain before publish
            if (tid == 0)
                __hip_atomic_fetch_add(&fL1[q], 1, __ATOMIC_RELAXED,
                                       __HIP_MEMORY_SCOPE_AGENT);
        }
    }
}

// ---------------------------------------------------------------- classifier
__global__ __launch_bounds__(256) void classifier(
    const bf16* __restrict__ Sring, const float* __restrict__ Wout,
    const float* __restrict__ bout, float* __restrict__ out)
{
    const int wave = threadIdx.x >> 6, lane = threadIdx.x & 63;
    const int row = blockIdx.x * 4 + wave;
    const int rg = row >> 7, loc = row & 127;
    const bf16* h1 = Sring + ((size_t)rg * RING + (128 % RING)) * SLAB
                     + (size_t)loc * K1 + 672;
    float acc[OUT_SZ] = {0.f, 0.f, 0.f, 0.f, 0.f};
    for (int k = lane; k < H_SZ; k += 64) {
        float h = __bfloat162float(h1[k]);
        #pragma unroll
        for (int o = 0; o < OUT_SZ; ++o) acc[o] += h * Wout[(size_t)o * H_SZ + k];
    }
    #pragma unroll
    for (int o = 0; o < OUT_SZ; ++o) {
        float v = acc[o];
        #pragma unroll
        for (int off = 32; off; off >>= 1) v += __shfl_down(v, off, 64);
        if (lane == 0) out[(size_t)row * OUT_SZ + o] = v + bout[o];
    }
}

// ---------------------------------------------------------------- launch

extern "C" void kernel_launch(void* const* d_in, const int* in_sizes, int n_in,
                              void* d_out, int out_size, void* d_ws, size_t ws_size,
                              hipStream_t stream) {
    const float* xs   = (const float*)d_in[0];
    const float* Wih0 = (const float*)d_in[1];
    const float* Whh0 = (const float*)d_in[2];
    const float* bih0 = (const float*)d_in[3];
    const float* bhh0 = (const float*)d_in[4];
    const float* Wih1 = (const float*)d_in[5];
    const float* Whh1 = (const float*)d_in[6];
    const float* bih1 = (const float*)d_in[7];
    const float* bhh1 = (const float*)d_in[8];
    const float* Wout = (const float*)d_in[9];
    const float* bout = (const float*)d_in[10];
    float* out = (float*)d_out;

    char* ws = (char*)d_ws;
    size_t off = 0;
    bf16* xs_pad = (bf16*)(ws + off); off += (size_t)T_STEPS * B_SZ * XK * 2;
    bf16* Wc0    = (bf16*)(ws + off); off += (size_t)N0PAD * K0 * 2;
    bf16* Wc1    = (bf16*)(ws + off); off += (size_t)N1PAD * K1 * 2;
    float* b0    = (float*)(ws + off); off += (size_t)N0PAD * 4;
    float* b1    = (float*)(ws + off); off += (size_t)N1PAD * 4;
    bf16* Sring  = (bf16*)(ws + off); off += (size_t)8 * RING * SLAB * 2;
    int*  flags  = (int*)(ws + off);  off += (size_t)16 * FSTR * 4;

    // ring (incl. zero-state slots + pad columns) and both flag arrays start zero
    hipMemsetAsync(Sring, 0, (size_t)8 * RING * SLAB * 2, stream);
    hipMemsetAsync(flags, 0, (size_t)16 * FSTR * 4, stream);

    prep_xs <<<(T_STEPS * B_SZ * XK + 255) / 256, 256, 0, stream>>>(xs, xs_pad);
    pack_w0 <<<(N0PAD * K0 + 255) / 256, 256, 0, stream>>>(Wih0, Whh0, Wc0);
    pack_w1 <<<(N1PAD * K1 + 255) / 256, 256, 0, stream>>>(Wih1, Whh1, Wc1);
    pack_bias<<<(N0PAD + 255) / 256, 256, 0, stream>>>(bih0, bhh0, b0, N0PAD);
    pack_bias<<<(N1PAD + 255) / 256, 256, 0, stream>>>(bih1, bhh1, b1, N1PAD);

    // dynamic LDS: max(L0) = 96 KB (W0) + 128*72*2 B (tile) = 116736 B
    hipFuncSetAttribute((const void*)persist,
                        hipFuncAttributeMaxDynamicSharedMemorySize, 116736);
    void* args[] = { (void*)&xs_pad, (void*)&Wc0, (void*)&Wc1, (void*)&b0,
                     (void*)&b1, (void*)&Sring, (void*)&flags };
    hipLaunchCooperativeKernel((const void*)persist, dim3(256), dim3(512),
                               args, 116736, stream);

    classifier<<<B_SZ / 4, 256, 0, stream>>>(Sring, Wout, bout, out);
}